// Round 5
// baseline (192.533 us; speedup 1.0000x reference)
//
#include <hip/hip_runtime.h>

// Flash attention fwd: fp32 I/O, bf16 MFMA, fp32 softmax math.
// BH=32, S=2048, D=64, additive mask [2,S,S] tiled bh%2.
// R13: R12 (swapped 32x32 QK^T, permlane P-redistribution, no sP, 32 KB
// LDS) + R8's mask scheduling. R12 regressed 98->110 vs R8 because mask
// loads moved to just-in-time inside each (t,gg) group: exp2 sat ~200-400
// cyc behind a fresh L3 load (mask is 32 MB, L3-resident), x4 groups x16
// iters with only 2 waves/SIMD to cover. Hoist all 4 groups' masks to the
// prefetch section (before __syncthreads) — barrier wait + QK chain covers
// L3 latency, as in R8. 64 extra VGPRs, static-indexed (stays in regs);
// <=256 is free at 2 blocks/CU. Decisive vs R8: only remaining diff is the
// sP-elimination structure.

constexpr int cBH = 32;
constexpr int cS  = 2048;
constexpr int cD  = 64;
constexpr int cQT = 128;            // 4 waves x 32 q-rows
constexpr int cNP = cS / 128;       // 16 pairs of 64-wide k-tiles

typedef __bf16 bf16x8 __attribute__((ext_vector_type(8)));
typedef __bf16 bf16x4 __attribute__((ext_vector_type(4)));
typedef float  f32x4  __attribute__((ext_vector_type(4)));
typedef float  f32x16 __attribute__((ext_vector_type(16)));
typedef unsigned int u32x4 __attribute__((ext_vector_type(4)));

__device__ __forceinline__ unsigned short bfbits(float f) {
    return __builtin_bit_cast(unsigned short, (__bf16)f);
}
__device__ __forceinline__ bf16x4 pack4(f32x4 a) {
    bf16x4 r;
    r[0] = (__bf16)a[0]; r[1] = (__bf16)a[1];
    r[2] = (__bf16)a[2]; r[3] = (__bf16)a[3];
    return r;
}
__device__ __forceinline__ bf16x8 pack8s(f32x4 a, f32x4 b, float s) {
    bf16x8 r;
    r[0] = (__bf16)(a[0]*s); r[1] = (__bf16)(a[1]*s);
    r[2] = (__bf16)(a[2]*s); r[3] = (__bf16)(a[3]*s);
    r[4] = (__bf16)(b[0]*s); r[5] = (__bf16)(b[1]*s);
    r[6] = (__bf16)(b[2]*s); r[7] = (__bf16)(b[3]*s);
    return r;
}
__device__ __forceinline__ int gkey(int d) {     // sV swizzle key (d 0..63)
    return (d ^ (d >> 3)) & 7;
}

__global__ __launch_bounds__(256, 2)
void sdpa_flash_kernel(const float* __restrict__ q,
                       const float* __restrict__ k,
                       const float* __restrict__ v,
                       const float* __restrict__ mask,
                       float* __restrict__ out)
{
    // sK[t]: [krow][d], swizzle key (krow&7)^((krow>>3&1)<<2) on 8-elem
    //        d-blocks (bit3 term keeps 32-row A-frag reads <=2-way).
    // sV[t]: [d][krow] (V^T), key gkey(d) on 8-elem k-blocks.
    __shared__ unsigned short sK[2][64 * 64];
    __shared__ unsigned short sV[2][64 * 64];

    const int tid  = threadIdx.x;
    const int wv   = tid >> 6;                          // 0..3
    const int lane = tid & 63;
    const int l31  = lane & 31;
    const int h    = lane >> 5;                         // 32-lane half
    const int swk  = (lane & 7) ^ (((lane >> 3) & 1) << 2);

    const int fid = blockIdx.x;
    const int bh  = (fid & 7) | ((fid >> 7) << 3);      // XCD-local heads
    const int qb  = ((fid >> 3) & 15) * cQT;
    const int mb  = bh & 1;

    const float L2E = 1.4426950408889634f;

    // ---- Q fragments (B-operand), pre-scaled by 0.125*log2(e) ----
    // lane holds Q[q = wv*32+l31][d = dc*16 + h*8 + 0..7]
    bf16x8 aq[4];
    {
        const float* qp = q + ((size_t)bh * cS + qb + wv * 32 + l31) * cD + h * 8;
#pragma unroll
        for (int dc = 0; dc < 4; ++dc)
            aq[dc] = pack8s(*(const f32x4*)(qp + dc * 16),
                            *(const f32x4*)(qp + dc * 16 + 4), 0.125f * L2E);
    }

    f32x16 acc[2] = {};       // O[q][d]: dg in {0,1} -> d = dg*32 + l31
    float lsum = 0.f;         // row-sum for q = l31 (half-k; merged at end)

    // ---- staging geometry: 256 threads; chunk j = floats j*1024 + tid*4 ----
    const int sr0 = tid >> 4;                 // 0..15
    const int c4  = (tid & 15) << 2;
    const int ka0 = sr0 * 64
        + ((((c4 >> 3) ^ (sr0 & 7) ^ (((sr0 >> 3) & 1) << 2)) << 3))
        + (c4 & 7);
    const float* kg = k + (size_t)bh * cS * cD;
    const float* vg = v + (size_t)bh * cS * cD;
    const float* mq = mask + (size_t)mb * cS * cS
                           + (size_t)(qb + wv * 32 + l31) * cS + h * 4;

    const int g0 = gkey(l31);
    const int g1 = gkey(32 + l31);
    const int vb0 = l31 * 64;
    const int vb1 = (32 + l31) * 64;

    // ---- prologue: stage pair 0 (tiles 0 and 1) directly ----
#pragma unroll
    for (int t = 0; t < 2; ++t)
#pragma unroll
        for (int j = 0; j < 4; ++j) {
            f32x4 kj = *(const f32x4*)(kg + t * 4096 + j * 1024 + tid * 4);
            f32x4 vj = *(const f32x4*)(vg + t * 4096 + j * 1024 + tid * 4);
            *(bf16x4*)&sK[t][ka0 + j * 1024] = pack4(kj);
#pragma unroll
            for (int i = 0; i < 4; ++i) {
                int d = c4 + i;
                sV[t][d * 64 + ((((j * 2) + (sr0 >> 3)) ^ gkey(d)) << 3) + (sr0 & 7)]
                    = bfbits(vj[i]);
            }
        }

    for (int pt = 0; pt < cNP; ++pt) {
        const int base = pt * 2;
        const bool more = (pt + 1 < cNP);
        const int nb = more ? base + 2 : base;      // clamped: uncond. loads

        // ---- prefetch next pair K/V into registers ----
        f32x4 KPe[4], VPe[4], KPo[4], VPo[4];
#pragma unroll
        for (int j = 0; j < 4; ++j) {
            KPe[j] = *(const f32x4*)(kg + (size_t)nb * 4096 + j * 1024 + tid * 4);
            VPe[j] = *(const f32x4*)(vg + (size_t)nb * 4096 + j * 1024 + tid * 4);
            KPo[j] = *(const f32x4*)(kg + (size_t)(nb + 1) * 4096 + j * 1024 + tid * 4);
            VPo[j] = *(const f32x4*)(vg + (size_t)(nb + 1) * 4096 + j * 1024 + tid * 4);
        }

        // ---- current pair's masks, ALL 4 groups, hoisted (R8 scheme):
        //      barrier wait + QK chain covers the L3 latency ----
        f32x4 mk[2][2][4];
#pragma unroll
        for (int t = 0; t < 2; ++t)
#pragma unroll
            for (int gg = 0; gg < 2; ++gg)
#pragma unroll
                for (int j = 0; j < 4; ++j)
                    mk[t][gg][j] = *(const f32x4*)(
                        mq + (size_t)(base + t) * 64 + gg * 32 + j * 8);

        __syncthreads();                            // pair staged & visible

#pragma unroll
        for (int t = 0; t < 2; ++t) {
            const unsigned short* sKt = sK[t];
            const unsigned short* sVt = sV[t];
#pragma unroll
            for (int gg = 0; gg < 2; ++gg) {
                // ---- QK^T swapped: S^T[k][q], A = K rows gg*32..+31 ----
                const int rb = (gg * 32 + l31) * 64;
                bf16x8 kf[4];
#pragma unroll
                for (int dc = 0; dc < 4; ++dc)
                    kf[dc] = *(const bf16x8*)(&sKt[rb + (((dc * 2 + h) ^ swk) << 3)]);
                f32x16 s = {};
#pragma unroll
                for (int dc = 0; dc < 4; ++dc)
                    s = __builtin_amdgcn_mfma_f32_32x32x16_bf16(kf[dc], aq[dc], s, 0, 0, 0);

                // ---- exp2(S + mask*log2e); k_local(r) = (r&3)+8*(r>>2)+4h ----
                float p[16];
#pragma unroll
                for (int r = 0; r < 16; ++r)
                    p[r] = __builtin_amdgcn_exp2f(
                        fmaf(mk[t][gg][r >> 2][r & 3], L2E, s[r]));
#pragma unroll
                for (int r = 0; r < 16; ++r)
                    lsum += p[r];

                // ---- pack to bf16 pairs; permlane32_swap builds A-frags ----
                unsigned int pk[8];
#pragma unroll
                for (int i = 0; i < 8; ++i)
                    pk[i] = (unsigned int)bfbits(p[2 * i])
                          | ((unsigned int)bfbits(p[2 * i + 1]) << 16);
                asm("v_permlane32_swap_b32 %0, %1" : "+v"(pk[0]), "+v"(pk[2]));
                asm("v_permlane32_swap_b32 %0, %1" : "+v"(pk[1]), "+v"(pk[3]));
                asm("v_permlane32_swap_b32 %0, %1" : "+v"(pk[4]), "+v"(pk[6]));
                asm("v_permlane32_swap_b32 %0, %1" : "+v"(pk[5]), "+v"(pk[7]));
                u32x4 ua = {pk[0], pk[1], pk[2], pk[3]};
                u32x4 ub = {pk[4], pk[5], pk[6], pk[7]};
                bf16x8 fA0 = __builtin_bit_cast(bf16x8, ua);   // k = gg*32 + 0..15
                bf16x8 fA1 = __builtin_bit_cast(bf16x8, ub);   // k = gg*32 + 16..31

                // ---- PV: O[q][d] += P V, B = V^T reads ----
#pragma unroll
                for (int kc = 0; kc < 2; ++kc) {
                    const int kb = gg * 4 + kc * 2 + h;
                    bf16x8 bv0 = *(const bf16x8*)(&sVt[vb0 + ((kb ^ g0) << 3)]);
                    bf16x8 bv1 = *(const bf16x8*)(&sVt[vb1 + ((kb ^ g1) << 3)]);
                    acc[0] = __builtin_amdgcn_mfma_f32_32x32x16_bf16(
                        kc ? fA1 : fA0, bv0, acc[0], 0, 0, 0);
                    acc[1] = __builtin_amdgcn_mfma_f32_32x32x16_bf16(
                        kc ? fA1 : fA0, bv1, acc[1], 0, 0, 0);
                }
            }
        }

        __syncthreads();                            // pair reads complete

        // ---- stage next pair from registers ----
        if (more) {
#pragma unroll
            for (int j = 0; j < 4; ++j) {
                *(bf16x4*)&sK[0][ka0 + j * 1024] = pack4(KPe[j]);
                *(bf16x4*)&sK[1][ka0 + j * 1024] = pack4(KPo[j]);
#pragma unroll
                for (int i = 0; i < 4; ++i) {
                    int d = c4 + i;
                    int va = d * 64 + ((((j * 2) + (sr0 >> 3)) ^ gkey(d)) << 3) + (sr0 & 7);
                    sV[0][va] = bfbits(VPe[j][i]);
                    sV[1][va] = bfbits(VPo[j][i]);
                }
            }
        }
    }

    // ---- epilogue: merge the two k-halves of lsum, then O = acc / l ----
    lsum += __shfl_xor(lsum, 32, 64);
#pragma unroll
    for (int r = 0; r < 16; ++r) {
        const int qrow = (r & 3) + 8 * (r >> 2) + 4 * h;
        const float rl = 1.0f / __shfl(lsum, qrow, 64);
        float* op = out + ((size_t)bh * cS + qb + wv * 32 + qrow) * cD + l31;
        op[0]  = acc[0][r] * rl;
        op[32] = acc[1][r] * rl;
    }
}

extern "C" void kernel_launch(void* const* d_in, const int* in_sizes, int n_in,
                              void* d_out, int out_size, void* d_ws, size_t ws_size,
                              hipStream_t stream) {
    const float* q = (const float*)d_in[0];
    const float* k = (const float*)d_in[1];
    const float* v = (const float*)d_in[2];
    const float* m = (const float*)d_in[3];
    float* o = (float*)d_out;
    sdpa_flash_kernel<<<dim3(512), 256, 0, stream>>>(q, k, v, m, o);
}